// Round 13
// baseline (191.406 us; speedup 1.0000x reference)
//
#include <hip/hip_runtime.h>
#include <cstdint>
#include <cstddef>

// Problem constants
#define NIMG 32
#define C    128
#define OC   128
#define HW   112
#define HWSZ (HW * HW)       // 12544
#define NTAP 9
#define PHW  114             // padded spatial dim
#define XROW (PHW * C)       // 14592 B per padded LDS row
#define AWQ_BYTES ((size_t)8 * 9 * 2 * 64 * 16) // 147,456

typedef int v4i  __attribute__((ext_vector_type(4)));

// ---------------------------------------------------------------------------
// Build A-fragments for mfma_i32_16x16x64_i8 (R6-proven layout):
// awq[f][lane][16B], f = ((o16*9 + tap)*2 + ks); lane l: row m = l&15,
// k = (l>>4)*16 + j.  A[m][k] = sign(w[o16*16+m][ks*64 + (l>>4)*16 + j][tap]).
__global__ void pack_w_frag(const float* __restrict__ w, uint32_t* __restrict__ awq) {
    int tid = blockIdx.x * blockDim.x + threadIdx.x;   // 144 frags * 256 dwords
    int d = tid & 3, l = (tid >> 2) & 63, f = tid >> 8;
    int ks = f & 1, tf = f >> 1;
    int tap = tf % 9, o16 = tf / 9;
    int o = o16 * 16 + (l & 15);
    int cb = ks * 64 + ((l >> 4) & 3) * 16 + d * 4;
    uint32_t acc = 0;
    #pragma unroll
    for (int jj = 0; jj < 4; ++jj) {
        uint32_t bits = __float_as_uint(w[(size_t)(o * C + cb + jj) * NTAP + tap]);
        acc |= (((bits >> 31) * 0xFEu) ^ 1u) << (8 * jj);
    }
    awq[tid] = acc;
}

// ---------------------------------------------------------------------------
// Fused binary conv, occupancy-first design (R12 + pointer-unit fix):
// - 512-thread blocks (8 waves), ONE output row each; 3584 XCD-swizzled blocks.
// - Each wave owns a 16-channel o-slab: A = 9 taps x 2 ks x v4i = 72 VGPR
//   (fits the 128-VGPR band -> 16 waves/CU; 2-3 blocks/CU by LDS 43776B).
// - Phase 1: stage 3 fp32 image rows, sign-pack to int8, conflict-free
//   swizzled LDS (slot (w+4h)^(col&7) per 128B col-line); borders zeroed.
// - Phase 2: 7 tiles of 16 px; per tile 18 ds_read_b128 + 18 MFMA 16x16x64.
__global__ __launch_bounds__(512) void bconv_fused(const float* __restrict__ x,
                                                   const uint8_t* __restrict__ awq,
                                                   float* __restrict__ out) {
    __shared__ __align__(16) uint8_t sxq[3 * XROW];    // 43776 B: rows h-1..h+1
    int bid = blockIdx.x;                              // 3584 = 8 * 448, bijective
    int swz = (bid & 7) * 448 + (bid >> 3);
    int n = swz / HW, h = swz % HW;

    int tid = threadIdx.x;
    int wv = tid >> 6, l = tid & 63;

    // ---- phase 1: load + sign-pack + conflict-free swizzled LDS stage ------
    if (tid < 336) {
        int r = tid / 112, rem = tid % 112;
        int w = rem & 3, pxg = rem >> 2;               // w lane-fastest
        int hr = h - 1 + r;                            // image row
        int col0 = 1 + pxg * 4;
        int sbase = r * XROW;
        if (hr >= 0 && hr < HW) {
            const float* xp = x + ((size_t)(n * C + w * 32)) * HWSZ
                                + (size_t)hr * HW + pxg * 4;
            uint32_t dw[4][8];
            #pragma unroll
            for (int j = 0; j < 4; ++j)
                #pragma unroll
                for (int d = 0; d < 8; ++d) dw[j][d] = 0u;
            #pragma unroll
            for (int c = 0; c < 32; ++c) {
                float4 v = *reinterpret_cast<const float4*>(xp + (size_t)c * HWSZ);
                uint32_t bm = 0xFFu << (8 * (c & 3));
                int d = c >> 2;
                dw[0][d] |= ((uint32_t)((int)__float_as_uint(v.x) >> 31)) & bm;
                dw[1][d] |= ((uint32_t)((int)__float_as_uint(v.y) >> 31)) & bm;
                dw[2][d] |= ((uint32_t)((int)__float_as_uint(v.z) >> 31)) & bm;
                dw[3][d] |= ((uint32_t)((int)__float_as_uint(v.w) >> 31)) & bm;
            }
            #pragma unroll
            for (int j = 0; j < 4; ++j) {
                int col = col0 + j;
                int c7 = col & 7;
                int line = sbase + col * 128;
                uint32_t d0 = (dw[j][0] & 0xFEFEFEFEu) ^ 0x01010101u;
                uint32_t d1 = (dw[j][1] & 0xFEFEFEFEu) ^ 0x01010101u;
                uint32_t d2 = (dw[j][2] & 0xFEFEFEFEu) ^ 0x01010101u;
                uint32_t d3 = (dw[j][3] & 0xFEFEFEFEu) ^ 0x01010101u;
                *(uint4*)&sxq[line + (((w)     ^ c7) << 4)] = make_uint4(d0, d1, d2, d3);
                uint32_t d4 = (dw[j][4] & 0xFEFEFEFEu) ^ 0x01010101u;
                uint32_t d5 = (dw[j][5] & 0xFEFEFEFEu) ^ 0x01010101u;
                uint32_t d6 = (dw[j][6] & 0xFEFEFEFEu) ^ 0x01010101u;
                uint32_t d7 = (dw[j][7] & 0xFEFEFEFEu) ^ 0x01010101u;
                *(uint4*)&sxq[line + (((w + 4) ^ c7) << 4)] = make_uint4(d4, d5, d6, d7);
            }
        } else {
            #pragma unroll
            for (int j = 0; j < 4; ++j) {
                int col = col0 + j;
                int c7 = col & 7;
                int line = sbase + col * 128;
                *(uint4*)&sxq[line + (((w)     ^ c7) << 4)] = make_uint4(0u, 0u, 0u, 0u);
                *(uint4*)&sxq[line + (((w + 4) ^ c7) << 4)] = make_uint4(0u, 0u, 0u, 0u);
            }
        }
    } else if (tid < 384) {
        // pad columns 0 and 113 of each staged row (3 rows x 2 cols x 8 slots)
        int j = tid - 336;
        int r = j >> 4, side = (j >> 3) & 1, k = j & 7;
        int col = side ? 113 : 0;
        *(uint4*)&sxq[r * XROW + col * 128 + k * 16] = make_uint4(0u, 0u, 0u, 0u);
    }

    // A-fragment loads (BYTE arithmetic -- this was R12's bug) ---------------
    v4i A[9][2];
    #pragma unroll
    for (int tap = 0; tap < 9; ++tap)
        #pragma unroll
        for (int ks = 0; ks < 2; ++ks) {
            int f = (wv * 9 + tap) * 2 + ks;
            A[tap][ks] = *(const v4i*)(awq + (size_t)f * 1024 + (size_t)l * 16);
        }
    __syncthreads();

    // ---- phase 2: 16x16x64 int8 MFMA over 7 N-tiles of 16 px ---------------
    int l15 = l & 15, g = l >> 4;
    float* outb = out + ((size_t)n * OC + wv * 16) * HWSZ + (size_t)h * HW;

    for (int nt = 0; nt < 7; ++nt) {
        int px = nt * 16 + l15;

        // slot for (ks, g): channels ks*64 + g*16 -> s = ks*2 + (g>>1) + 4*(g&1)
        int sbase0 = (g >> 1) + 4 * (g & 1);
        int ad[3][2];
        #pragma unroll
        for (int kw = 0; kw < 3; ++kw) {
            int col = px + kw;                         // <= 113, in-bounds
            int c7 = col & 7;
            int line = col * 128;
            ad[kw][0] = line + (((sbase0)     ^ c7) << 4);
            ad[kw][1] = line + (((sbase0 + 2) ^ c7) << 4);
        }

        v4i acc = {0, 0, 0, 0};
        #pragma unroll
        for (int kh = 0; kh < 3; ++kh)
            #pragma unroll
            for (int kw = 0; kw < 3; ++kw)
                #pragma unroll
                for (int ks = 0; ks < 2; ++ks) {
                    v4i b = *(const v4i*)&sxq[kh * XROW + ad[kw][ks]];
                    acc = __builtin_amdgcn_mfma_i32_16x16x64_i8(
                              A[kh * 3 + kw][ks], b, acc, 0, 0, 0);
                }

        #pragma unroll
        for (int r = 0; r < 4; ++r) {
            int oof = g * 4 + r;                       // D: col=l&15, row=g*4+r
            outb[(size_t)oof * HWSZ + px] = (float)acc[r];
        }
    }
}

// ===========================================================================
extern "C" void kernel_launch(void* const* d_in, const int* in_sizes, int n_in,
                              void* d_out, int out_size, void* d_ws, size_t ws_size,
                              hipStream_t stream) {
    const float* x   = (const float*)d_in[0];
    const float* wts = (const float*)d_in[1];
    float* out = (float*)d_out;
    uint32_t* awq = (uint32_t*)d_ws;

    hipLaunchKernelGGL(pack_w_frag, dim3(144), dim3(256), 0, stream, wts, awq);
    hipLaunchKernelGGL(bconv_fused, dim3(NIMG * HW), dim3(512), 0, stream,
                       x, (const uint8_t*)awq, out);
}

// Round 14
// 145.849 us; speedup vs baseline: 1.3124x; 1.3124x over previous
//
#include <hip/hip_runtime.h>
#include <cstdint>
#include <cstddef>

// Problem constants
#define NIMG 32
#define C    128
#define OC   128
#define HW   112
#define HWSZ (HW * HW)       // 12544
#define NTAP 9
#define XROW (114 * 128)     // 14592 B per padded LDS row-slot
#define ROWS 7               // output rows per block strip
#define NSTRIP (HW / ROWS)   // 16 strips per image
#define AWQ_BYTES ((size_t)8 * 9 * 2 * 64 * 16) // 147,456

typedef int v4i __attribute__((ext_vector_type(4)));

// ---------------------------------------------------------------------------
// Build A-fragments for mfma_i32_16x16x64_i8 (R6/R13-proven layout):
// awq[f][lane][16B], f = ((o16*9 + tap)*2 + ks); lane l: row m = l&15,
// k = (l>>4)*16 + j.  A[m][k] = sign(w[o16*16+m][ks*64 + (l>>4)*16 + j][tap]).
__global__ void pack_w_frag(const float* __restrict__ w, uint32_t* __restrict__ awq) {
    int tid = blockIdx.x * blockDim.x + threadIdx.x;   // 144 frags * 256 dwords
    int d = tid & 3, l = (tid >> 2) & 63, f = tid >> 8;
    int ks = f & 1, tf = f >> 1;
    int tap = tf % 9, o16 = tf / 9;
    int o = o16 * 16 + (l & 15);
    int cb = ks * 64 + ((l >> 4) & 3) * 16 + d * 4;
    uint32_t acc = 0;
    #pragma unroll
    for (int jj = 0; jj < 4; ++jj) {
        uint32_t bits = __float_as_uint(w[(size_t)(o * C + cb + jj) * NTAP + tap]);
        acc |= (((bits >> 31) * 0xFEu) ^ 1u) << (8 * jj);
    }
    awq[tid] = acc;
}

// ---------------------------------------------------------------------------
__device__ __forceinline__ uint32_t fixsb(uint32_t u) {
    // per-byte: 0x00 (x>=0) -> 0x01 (+1); 0xFF (x<0) -> 0xFF (-1)
    return (u & 0xFEFEFEFEu) ^ 0x01010101u;
}

__device__ __forceinline__ void pack8(const float4* va, uint32_t pk[4][2]) {
    #pragma unroll
    for (int jj = 0; jj < 4; ++jj) { pk[jj][0] = 0u; pk[jj][1] = 0u; }
    #pragma unroll
    for (int c = 0; c < 8; ++c) {
        uint32_t bm = 0xFFu << (8 * (c & 3));
        int d = c >> 2;
        pk[0][d] |= (uint32_t)((int)__float_as_uint(va[c].x) >> 31) & bm;
        pk[1][d] |= (uint32_t)((int)__float_as_uint(va[c].y) >> 31) & bm;
        pk[2][d] |= (uint32_t)((int)__float_as_uint(va[c].z) >> 31) & bm;
        pk[3][d] |= (uint32_t)((int)__float_as_uint(va[c].w) >> 31) & bm;
    }
}

// Tile compute: 16 px, 2 o-tiles, K=128 over 9 taps (B from LDS ring).
#define TILES(NT0, NT1)                                                        \
    _Pragma("unroll")                                                          \
    for (int nt = (NT0); nt < (NT1); ++nt) {                                   \
        int px = nt * 16 + l15;                                                \
        int ad[3][2];                                                          \
        _Pragma("unroll")                                                      \
        for (int kw = 0; kw < 3; ++kw) {                                       \
            int col = px + kw, c7 = col & 7;                                   \
            ad[kw][0] = col * 128 + (((sb0)     ^ c7) << 4);                   \
            ad[kw][1] = col * 128 + (((sb0 + 2) ^ c7) << 4);                   \
        }                                                                      \
        v4i acc0 = {0, 0, 0, 0}, acc1 = {0, 0, 0, 0};                          \
        _Pragma("unroll")                                                      \
        for (int kh = 0; kh < 3; ++kh) {                                       \
            const uint8_t* sbp = ring + ((r + kh) & 3) * XROW;                 \
            _Pragma("unroll")                                                  \
            for (int kw = 0; kw < 3; ++kw)                                     \
                _Pragma("unroll")                                              \
                for (int ks = 0; ks < 2; ++ks) {                               \
                    v4i b = *(const v4i*)&sbp[ad[kw][ks]];                     \
                    acc0 = __builtin_amdgcn_mfma_i32_16x16x64_i8(              \
                               A[0][kh * 3 + kw][ks], b, acc0, 0, 0, 0);       \
                    acc1 = __builtin_amdgcn_mfma_i32_16x16x64_i8(              \
                               A[1][kh * 3 + kw][ks], b, acc1, 0, 0, 0);       \
                }                                                              \
        }                                                                      \
        _Pragma("unroll")                                                      \
        for (int rr = 0; rr < 4; ++rr) {                                       \
            int oo = g * 4 + rr;                                               \
            outrow[(size_t)oo * HWSZ + px]        = (float)acc0[rr];           \
            outrow[(size_t)(oo + 16) * HWSZ + px] = (float)acc1[rr];           \
        }                                                                      \
    }

// ---------------------------------------------------------------------------
// Row-pipelined fused binary conv.
// Block = 256 thr (4 waves x 32 o), strip of 7 output rows, LDS ring of 4
// row-slots.  Per iter r: issue loads(row r+2) -> tiles 0-3 -> packA +
// issue 8 more -> tiles 4-6 -> packB + swizzled ds_write(slot (r+3)&3) ->
// ONE barrier.  Ring disjointness: reads slots r..r+2, writes (r+3)&3.
// HBM load latency hides under ~5000cyc of MFMA per row (T14 recipe).
__global__ __launch_bounds__(256) void bconv_pipe(const float* __restrict__ x,
                                                  const uint8_t* __restrict__ awq,
                                                  float* __restrict__ out) {
    __shared__ __align__(16) uint8_t ring[4 * XROW];   // 58368 B
    int bid = blockIdx.x;                              // 512 = 8 * 64, bijective
    int swz = (bid & 7) * 64 + (bid >> 3);
    int n = swz >> 4, strip = swz & 15;
    int h0 = strip * ROWS;

    int t = threadIdx.x;
    int wv = t >> 6, l = t & 63;
    int l15 = l & 15, g = l >> 4;
    int sb0 = (g >> 1) + 4 * (g & 1);

    // A-fragments: 2 o-tiles x 9 taps x 2 ks (144 regs; MFMA reads AGPR A directly)
    v4i A[2][9][2];
    #pragma unroll
    for (int ot = 0; ot < 2; ++ot)
        #pragma unroll
        for (int tap = 0; tap < 9; ++tap)
            #pragma unroll
            for (int ks = 0; ks < 2; ++ks) {
                int f = ((wv * 2 + ot) * 9 + tap) * 2 + ks;
                A[ot][tap][ks] = *(const v4i*)(awq + (size_t)f * 1024 + (size_t)l * 16);
            }

    // staging role: (32-ch group sw, 16-ch half chh, 4-px group pxg)
    int sw = t & 3, chh = (t >> 2) & 1, pxg = t >> 3;
    bool stager = (pxg < 28);
    int chbase = sw * 32 + chh * 16;
    int colbase = 1 + pxg * 4;
    int slotsel = sw + 4 * chh;
    const float* xbase = x + (size_t)(n * C + chbase) * HWSZ;

    // zero border cols (0,113) of all 4 slots: threads 224..255, 2 uint4 each
    if (!stager) {
        int k = t - 224;
        #pragma unroll
        for (int u = 0; u < 2; ++u) {
            int v = k * 2 + u;                         // 0..63
            int slot = v >> 4, rest = v & 15;
            int col = (rest >> 3) ? 113 : 0;
            int q = rest & 7;
            *(uint4*)&ring[slot * XROW + col * 128 + q * 16] = make_uint4(0u, 0u, 0u, 0u);
        }
    }

    // prologue: stage rows j=-1,0,1 into slots 0,1,2 (latency exposed, once)
    #pragma unroll
    for (int j = -1; j <= 1; ++j) {
        if (stager) {
            int hr = h0 + j;
            uint8_t* sbp = ring + ((j + 1) & 3) * XROW;
            uint32_t pkA[4][2] = {}, pkB[4][2] = {};
            bool ok = (hr >= 0) && (hr < HW);
            if (ok) {
                const float* xp = xbase + (size_t)hr * HW + pxg * 4;
                float4 va[8];
                #pragma unroll
                for (int c = 0; c < 8; ++c) va[c] = *(const float4*)(xp + (size_t)c * HWSZ);
                pack8(va, pkA);
                #pragma unroll
                for (int c = 0; c < 8; ++c) va[c] = *(const float4*)(xp + (size_t)(c + 8) * HWSZ);
                pack8(va, pkB);
            }
            #pragma unroll
            for (int jj = 0; jj < 4; ++jj) {
                int col = colbase + jj, c7 = col & 7;
                uint4 q = ok ? make_uint4(fixsb(pkA[jj][0]), fixsb(pkA[jj][1]),
                                          fixsb(pkB[jj][0]), fixsb(pkB[jj][1]))
                             : make_uint4(0u, 0u, 0u, 0u);
                *(uint4*)&sbp[col * 128 + ((slotsel ^ c7) << 4)] = q;
            }
        }
    }
    __syncthreads();

    // main pipelined loop
    for (int r = 0; r < ROWS; ++r) {
        bool do_stage = stager && (r + 2 <= ROWS);
        int hr2 = h0 + r + 2;                          // >= 2, so only upper bound
        bool inr = do_stage && (hr2 < HW);
        const float* xp = xbase + (size_t)hr2 * HW + pxg * 4;
        float4 va[8];
        uint32_t pkA[4][2] = {}, pkB[4][2] = {};

        if (inr) {
            #pragma unroll
            for (int c = 0; c < 8; ++c) va[c] = *(const float4*)(xp + (size_t)c * HWSZ);
        }

        float* outrow = out + (size_t)(n * OC + wv * 32) * HWSZ + (size_t)(h0 + r) * HW;

        TILES(0, 4)

        if (inr) {
            pack8(va, pkA);
            #pragma unroll
            for (int c = 0; c < 8; ++c) va[c] = *(const float4*)(xp + (size_t)(c + 8) * HWSZ);
        }

        TILES(4, 7)

        if (do_stage) {
            if (inr) pack8(va, pkB);
            uint8_t* sbp = ring + ((r + 3) & 3) * XROW;
            #pragma unroll
            for (int jj = 0; jj < 4; ++jj) {
                int col = colbase + jj, c7 = col & 7;
                uint4 q = inr ? make_uint4(fixsb(pkA[jj][0]), fixsb(pkA[jj][1]),
                                           fixsb(pkB[jj][0]), fixsb(pkB[jj][1]))
                              : make_uint4(0u, 0u, 0u, 0u);
                *(uint4*)&sbp[col * 128 + ((slotsel ^ c7) << 4)] = q;
            }
        }
        __syncthreads();
    }
}

// ===========================================================================
extern "C" void kernel_launch(void* const* d_in, const int* in_sizes, int n_in,
                              void* d_out, int out_size, void* d_ws, size_t ws_size,
                              hipStream_t stream) {
    const float* x   = (const float*)d_in[0];
    const float* wts = (const float*)d_in[1];
    float* out = (float*)d_out;
    uint32_t* awq = (uint32_t*)d_ws;

    hipLaunchKernelGGL(pack_w_frag, dim3(144), dim3(256), 0, stream, wts, awq);
    hipLaunchKernelGGL(bconv_pipe, dim3(NIMG * NSTRIP), dim3(256), 0, stream,
                       x, (const uint8_t*)awq, out);
}